// Round 7
// baseline (625.451 us; speedup 1.0000x reference)
//
#include <hip/hip_runtime.h>
#include <hip/hip_bf16.h>
#include <stdint.h>
#include <string.h>

#define NN 50000
#define NE 800000

typedef short bf8_t __attribute__((ext_vector_type(8)));
typedef float f32x4 __attribute__((ext_vector_type(4)));

// silu via native exp + v_rcp
__device__ __forceinline__ float silu_f(float v) {
    return v * __builtin_amdgcn_rcpf(1.0f + __expf(-v));
}

__device__ __forceinline__ unsigned int pack2bf(float a, float b) {
    __hip_bfloat162 h = __float22bfloat162_rn(make_float2(a, b));   // v_cvt_pk_bf16_f32
    unsigned int u; memcpy(&u, &h, 4);
    return u;
}

__device__ __forceinline__ float bf_lo(unsigned int u) { return __uint_as_float(u << 16); }
__device__ __forceinline__ float bf_hi(unsigned int u) { return __uint_as_float(u & 0xffff0000u); }

union U4B { uint4 u; bf8_t b; };
__device__ __forceinline__ bf8_t as_bf8(uint4 u) { U4B x; x.u = u; return x.b; }

__device__ __forceinline__ int kth_bit64(unsigned long long m, int k) {
    for (int i = 0; i < k; ++i) m &= m - 1;
    return __ffsll((long long)m) - 1;
}

// ---------------------------------------------------------------------------
// prep: x f32 -> bf16, fused with edge-row histogram
// ---------------------------------------------------------------------------
__global__ __launch_bounds__(256) void prep_x_hist(const float* __restrict__ x,
                                                   unsigned short* __restrict__ xbf,
                                                   const int* __restrict__ ei,
                                                   int* __restrict__ cnt) {
    size_t i = (size_t)blockIdx.x * 256 + threadIdx.x;
    const float4* s = (const float4*)(x + i * 8);
    float4 v0 = s[0], v1 = s[1];
    uint4 o;
    o.x = pack2bf(v0.x, v0.y); o.y = pack2bf(v0.z, v0.w);
    o.z = pack2bf(v1.x, v1.y); o.w = pack2bf(v1.z, v1.w);
    *(uint4*)(xbf + i * 8) = o;
    atomicAdd(&cnt[ei[i]], 1);
}

// ---------------------------------------------------------------------------
// prep: weight fragments in MFMA A-operand order (W^T), bf16.
// ---------------------------------------------------------------------------
__global__ __launch_bounds__(64) void prep_w(const float* __restrict__ We1,
                                             const float* __restrict__ We2,
                                             const float* __restrict__ Wn1,
                                             const float* __restrict__ Wn2,
                                             unsigned short* __restrict__ wf1,
                                             unsigned short* __restrict__ wf2,
                                             unsigned short* __restrict__ wfn1,
                                             unsigned short* __restrict__ wfn2) {
    int b = blockIdx.x, lane = threadIdx.x;
    int q = lane >> 4, c = lane & 15;
    const float* W; unsigned short* dst; int f;
    if (b < 64)       { W = We1; f = b;       dst = wf1  + (size_t)f * 512; }
    else if (b < 96)  { W = We2; f = b - 64;  dst = wf2  + (size_t)f * 512; }
    else if (b < 160) { W = Wn1; f = b - 96;  dst = wfn1 + (size_t)f * 512; }
    else              { W = Wn2; f = b - 160; dst = wfn2 + (size_t)f * 512; }
    int s = f >> 3, mf = f & 7;
    int k0 = s * 32 + q * 8, col = mf * 16 + c;
    float v[8];
    #pragma unroll
    for (int i = 0; i < 8; ++i) v[i] = W[(size_t)(k0 + i) * 128 + col];
    uint4 o;
    o.x = pack2bf(v[0], v[1]); o.y = pack2bf(v[2], v[3]);
    o.z = pack2bf(v[4], v[5]); o.w = pack2bf(v[6], v[7]);
    *(uint4*)(dst + lane * 8) = o;
}

// ---------------------------------------------------------------------------
// CSR build
// ---------------------------------------------------------------------------
__global__ __launch_bounds__(1024) void egnn_scan(const int* __restrict__ cnt,
                                                  int* __restrict__ off,
                                                  int* __restrict__ cur) {
    __shared__ int part[1024];
    const int t = threadIdx.x;
    const int CH = (NN + 1023) / 1024;
    int lo = t * CH, hi = lo + CH; if (hi > NN) hi = NN; if (lo > NN) lo = NN;
    int s = 0;
    for (int i = lo; i < hi; ++i) s += cnt[i];
    part[t] = s;
    __syncthreads();
    for (int d = 1; d < 1024; d <<= 1) {
        int v = (t >= d) ? part[t - d] : 0;
        __syncthreads();
        part[t] += v;
        __syncthreads();
    }
    int base = (t == 0) ? 0 : part[t - 1];
    for (int i = lo; i < hi; ++i) { off[i] = base; cur[i] = base; base += cnt[i]; }
    if (t == 1023) off[NN] = NE;
}

// scatter: materialize (row,col) pairs in CSR slot order as int2
__global__ __launch_bounds__(256) void egnn_scatter(const int* __restrict__ ei,
                                                    int* __restrict__ cur,
                                                    int2* __restrict__ rc_slot) {
    int e = blockIdx.x * 256 + threadIdx.x;
    if (e < NE) {
        int r = ei[e];
        int p = atomicAdd(&cur[r], 1);
        rc_slot[p] = make_int2(r, ei[NE + e]);
    }
}

// ---------------------------------------------------------------------------
// Edge MFMA kernel with fused segmented aggregation.
// Block = 64 CSR slots, 256 threads = 4 waves (P = col-quarter).
// ---------------------------------------------------------------------------
__global__ __launch_bounds__(256, 8) void egnn_edge_mfma(
    const unsigned short* __restrict__ xbf, const float* __restrict__ pos,
    const unsigned short* __restrict__ wf1, const unsigned short* __restrict__ wf2,
    const float* __restrict__ We1, const float* __restrict__ be1,
    const float* __restrict__ be2, const float* __restrict__ Wc,
    const float* __restrict__ bc,
    const int2* __restrict__ rc_slot,
    float* __restrict__ agg, float* __restrict__ delta)
{
    __shared__ __align__(16) char HsBuf[64 * 136 * 2];    // h1 tile, later m tile
    unsigned short* Hs = (unsigned short*)HsBuf;          // stride 136 (u16)
    unsigned int*  mls = (unsigned int*)HsBuf;            // stride 66  (u32)
    __shared__ int   rows_s[64], cols_s[64];
    __shared__ float rij_s[64][3];                        // becomes trans in place
    __shared__ float dij_s[64];
    __shared__ float wdot[64];
    __shared__ unsigned long long smask;
    __shared__ int firstPartial, lastPartial;

    const int tid = threadIdx.x;
    const int e0 = blockIdx.x * 64;

    if (tid < 64) {
        int2 rc = rc_slot[e0 + tid];
        rows_s[tid] = rc.x; cols_s[tid] = rc.y;
        float d = 0.f;
        #pragma unroll
        for (int k = 0; k < 3; ++k) {
            float rv = pos[rc.x * 3 + k] - pos[rc.y * 3 + k];
            rij_s[tid][k] = rv; d += rv * rv;
        }
        dij_s[tid] = d;
        wdot[tid] = 0.f;
    }
    __syncthreads();

    const int P = tid >> 6, lane = tid & 63;
    const int q = lane >> 4, e16 = lane & 15;
    const int oc_q = P * 32 + q * 4;

    int ridx[4], cidx[4], eloc[4];
    #pragma unroll
    for (int t = 0; t < 4; ++t) {
        int el = t * 16 + e16; eloc[t] = el;
        ridx[t] = rows_s[el]; cidx[t] = cols_s[el];
    }

    // ---- layer 1: K=256 MFMA; dij rank-1 + bias as f32 fixup ----
    f32x4 acc[2][4];
    #pragma unroll
    for (int M = 0; M < 2; ++M) {
        float4 bi = *(const float4*)(be1 + oc_q + M * 16);
        #pragma unroll
        for (int t = 0; t < 4; ++t) { acc[M][t][0] = bi.x; acc[M][t][1] = bi.y; acc[M][t][2] = bi.z; acc[M][t][3] = bi.w; }
    }

    #pragma unroll
    for (int s = 0; s < 8; ++s) {
        bf8_t bfr[4];
        #pragma unroll
        for (int t = 0; t < 4; ++t) {
            int node = (s < 4) ? ridx[t] : cidx[t];
            bfr[t] = as_bf8(*(const uint4*)(xbf + (size_t)node * 128 + (s & 3) * 32 + q * 8));
        }
        #pragma unroll
        for (int M = 0; M < 2; ++M) {
            bf8_t af = as_bf8(*(const uint4*)(wf1 + (size_t)(s * 8 + P * 2 + M) * 512 + lane * 8));
            #pragma unroll
            for (int t = 0; t < 4; ++t)
                acc[M][t] = __builtin_amdgcn_mfma_f32_16x16x32_bf16(af, bfr[t], acc[M][t], 0, 0, 0);
        }
    }

    #pragma unroll
    for (int M = 0; M < 2; ++M) {
        float4 w256 = *(const float4*)(We1 + (size_t)256 * 128 + oc_q + M * 16);
        #pragma unroll
        for (int t = 0; t < 4; ++t) {
            float d = dij_s[eloc[t]];
            float v0 = silu_f(acc[M][t][0] + d * w256.x);
            float v1 = silu_f(acc[M][t][1] + d * w256.y);
            float v2 = silu_f(acc[M][t][2] + d * w256.z);
            float v3 = silu_f(acc[M][t][3] + d * w256.w);
            uint2 pk; pk.x = pack2bf(v0, v1); pk.y = pack2bf(v2, v3);
            *(uint2*)(Hs + (size_t)eloc[t] * 136 + oc_q + M * 16) = pk;
        }
    }
    __syncthreads();

    // ---- layer 2: K=128 ----
    f32x4 acc2[2][4];
    #pragma unroll
    for (int M = 0; M < 2; ++M) {
        float4 bi = *(const float4*)(be2 + oc_q + M * 16);
        #pragma unroll
        for (int t = 0; t < 4; ++t) { acc2[M][t][0] = bi.x; acc2[M][t][1] = bi.y; acc2[M][t][2] = bi.z; acc2[M][t][3] = bi.w; }
    }

    #pragma unroll
    for (int s = 0; s < 4; ++s) {
        bf8_t bfr[4];
        #pragma unroll
        for (int t = 0; t < 4; ++t)
            bfr[t] = as_bf8(*(const uint4*)(Hs + (size_t)eloc[t] * 136 + s * 32 + q * 8));
        #pragma unroll
        for (int M = 0; M < 2; ++M) {
            bf8_t af = as_bf8(*(const uint4*)(wf2 + (size_t)(s * 8 + P * 2 + M) * 512 + lane * 8));
            #pragma unroll
            for (int t = 0; t < 4; ++t)
                acc2[M][t] = __builtin_amdgcn_mfma_f32_16x16x32_bf16(af, bfr[t], acc2[M][t], 0, 0, 0);
        }
    }
    __syncthreads();   // all Hs reads done before m overwrites the buffer

    // ---- epilogue: m = silu(.) -> LDS (mls); per-slot Wc dot partials ----
    float4 wcA = *(const float4*)(Wc + oc_q);
    float4 wcB = *(const float4*)(Wc + oc_q + 16);
    float part[4];
    #pragma unroll
    for (int t = 0; t < 4; ++t) part[t] = 0.f;

    #pragma unroll
    for (int M = 0; M < 2; ++M) {
        float4 wc = (M == 0) ? wcA : wcB;
        #pragma unroll
        for (int t = 0; t < 4; ++t) {
            float v0 = silu_f(acc2[M][t][0]);
            float v1 = silu_f(acc2[M][t][1]);
            float v2 = silu_f(acc2[M][t][2]);
            float v3 = silu_f(acc2[M][t][3]);
            part[t] += v0 * wc.x + v1 * wc.y + v2 * wc.z + v3 * wc.w;
            mls[(size_t)eloc[t] * 66 + P * 16 + M * 8 + q * 2]     = pack2bf(v0, v1);
            mls[(size_t)eloc[t] * 66 + P * 16 + M * 8 + q * 2 + 1] = pack2bf(v2, v3);
        }
    }
    #pragma unroll
    for (int t = 0; t < 4; ++t) {
        float p = part[t];
        p += __shfl_xor(p, 16);
        p += __shfl_xor(p, 32);
        if (q == 0) atomicAdd(&wdot[eloc[t]], p);
    }
    __syncthreads();   // mls + wdot complete

    // ---- per-slot trans (in place) + segment boundary detection ----
    if (tid < 64) {
        float wgt = silu_f(wdot[tid] + bc[0]);
        rij_s[tid][0] *= wgt; rij_s[tid][1] *= wgt; rij_s[tid][2] *= wgt;
        bool flag = (tid == 0) || (rows_s[tid] != rows_s[tid - 1]);
        unsigned long long b = __ballot(flag);
        if (lane == 0) {
            smask = b;
            firstPartial = (e0 > 0) && (rc_slot[e0 - 1].x == rows_s[0]);
            lastPartial  = (e0 + 64 < NE) && (rc_slot[e0 + 64].x == rows_s[63]);
        }
    }
    __syncthreads();

    // ---- segmented reduction: 4 groups x 64 col-pairs ----
    {
        const int c2 = tid & 63;          // u32 col pair -> cols 2c2, 2c2+1
        const int g  = tid >> 6;          // segment round-robin group
        unsigned long long m = smask;
        int nseg = __popcll(m);
        for (int k = g; k < nseg; k += 4) {
            int start = kth_bit64(m, k);
            int end   = (k + 1 < nseg) ? kth_bit64(m, k + 1) : 64;
            int node  = rows_s[start];
            float a0 = 0.f, a1 = 0.f;
            for (int s2 = start; s2 < end; ++s2) {
                unsigned int u = mls[(size_t)s2 * 66 + c2];
                a0 += bf_lo(u); a1 += bf_hi(u);
            }
            bool partial = (k == 0 && firstPartial) || (k == nseg - 1 && lastPartial);
            float* dst = agg + (size_t)node * 128 + c2 * 2;
            if (partial) { atomicAdd(dst, a0); atomicAdd(dst + 1, a1); }
            else         { *(float2*)dst = make_float2(a0, a1); }
            if (c2 == 0) {
                float d0 = 0.f, d1 = 0.f, d2 = 0.f;
                for (int s2 = start; s2 < end; ++s2) {
                    d0 += rij_s[s2][0]; d1 += rij_s[s2][1]; d2 += rij_s[s2][2];
                }
                float* dd = delta + (size_t)node * 3;
                if (partial) { atomicAdd(dd, d0); atomicAdd(dd + 1, d1); atomicAdd(dd + 2, d2); }
                else         { dd[0] = d0; dd[1] = d1; dd[2] = d2; }
            }
        }
    }
}

// ---------------------------------------------------------------------------
// Node MFMA kernel: x_new = silu([x|agg] @ Wn1 + bn1) @ Wn2 + bn2
// Reads agg f32 directly (in-register cvt); also writes pos_new.
// ---------------------------------------------------------------------------
__global__ __launch_bounds__(512, 4) void egnn_node_mfma(
    const unsigned short* __restrict__ xbf, const float* __restrict__ agg,
    const float* __restrict__ delta, const float* __restrict__ pos,
    const unsigned short* __restrict__ wfn1, const unsigned short* __restrict__ wfn2,
    const float* __restrict__ bn1, const float* __restrict__ bn2,
    float* __restrict__ out)
{
    __shared__ unsigned short Hs[128 * 136];

    const int tid = threadIdx.x;
    const int n0 = blockIdx.x * 128;

    // pos_new for this block's nodes (independent of the MLP)
    if (tid < 384) {
        int n = n0 + tid / 3, d = tid - 3 * (tid / 3);
        if (n < NN)
            out[(size_t)NN * 128 + (size_t)n * 3 + d] =
                pos[(size_t)n * 3 + d] + 0.01f * delta[(size_t)n * 3 + d];
    }

    const int w = tid >> 6, lane = tid & 63;
    const int P = w & 3, Q = w >> 2;
    const int q = lane >> 4, e16 = lane & 15;
    const int oc_q = P * 32 + q * 4;

    int nloc[4], nclamp[4];
    #pragma unroll
    for (int t = 0; t < 4; ++t) {
        int nl = Q * 64 + t * 16 + e16; nloc[t] = nl;
        int node = n0 + nl; nclamp[t] = (node >= NN) ? NN - 1 : node;
    }

    f32x4 acc[2][4];
    #pragma unroll
    for (int M = 0; M < 2; ++M) {
        float4 bi = *(const float4*)(bn1 + oc_q + M * 16);
        #pragma unroll
        for (int t = 0; t < 4; ++t) { acc[M][t][0] = bi.x; acc[M][t][1] = bi.y; acc[M][t][2] = bi.z; acc[M][t][3] = bi.w; }
    }

    #pragma unroll
    for (int s = 0; s < 8; ++s) {
        bf8_t bfr[4];
        #pragma unroll
        for (int t = 0; t < 4; ++t) {
            if (s < 4) {
                bfr[t] = as_bf8(*(const uint4*)(xbf + (size_t)nclamp[t] * 128 + (s & 3) * 32 + q * 8));
            } else {
                const float* base = agg + (size_t)nclamp[t] * 128 + (s & 3) * 32 + q * 8;
                float4 a0 = *(const float4*)base;
                float4 a1 = *(const float4*)(base + 4);
                uint4 o;
                o.x = pack2bf(a0.x, a0.y); o.y = pack2bf(a0.z, a0.w);
                o.z = pack2bf(a1.x, a1.y); o.w = pack2bf(a1.z, a1.w);
                bfr[t] = as_bf8(o);
            }
        }
        #pragma unroll
        for (int M = 0; M < 2; ++M) {
            bf8_t af = as_bf8(*(const uint4*)(wfn1 + (size_t)(s * 8 + P * 2 + M) * 512 + lane * 8));
            #pragma unroll
            for (int t = 0; t < 4; ++t)
                acc[M][t] = __builtin_amdgcn_mfma_f32_16x16x32_bf16(af, bfr[t], acc[M][t], 0, 0, 0);
        }
    }

    #pragma unroll
    for (int M = 0; M < 2; ++M) {
        #pragma unroll
        for (int t = 0; t < 4; ++t) {
            float v0 = silu_f(acc[M][t][0]);
            float v1 = silu_f(acc[M][t][1]);
            float v2 = silu_f(acc[M][t][2]);
            float v3 = silu_f(acc[M][t][3]);
            uint2 pk; pk.x = pack2bf(v0, v1); pk.y = pack2bf(v2, v3);
            *(uint2*)(Hs + (size_t)nloc[t] * 136 + oc_q + M * 16) = pk;
        }
    }
    __syncthreads();

    f32x4 acc2[2][4];
    #pragma unroll
    for (int M = 0; M < 2; ++M) {
        float4 bi = *(const float4*)(bn2 + oc_q + M * 16);
        #pragma unroll
        for (int t = 0; t < 4; ++t) { acc2[M][t][0] = bi.x; acc2[M][t][1] = bi.y; acc2[M][t][2] = bi.z; acc2[M][t][3] = bi.w; }
    }

    #pragma unroll
    for (int s = 0; s < 4; ++s) {
        bf8_t bfr[4];
        #pragma unroll
        for (int t = 0; t < 4; ++t)
            bfr[t] = as_bf8(*(const uint4*)(Hs + (size_t)nloc[t] * 136 + s * 32 + q * 8));
        #pragma unroll
        for (int M = 0; M < 2; ++M) {
            bf8_t af = as_bf8(*(const uint4*)(wfn2 + (size_t)(s * 8 + P * 2 + M) * 512 + lane * 8));
            #pragma unroll
            for (int t = 0; t < 4; ++t)
                acc2[M][t] = __builtin_amdgcn_mfma_f32_16x16x32_bf16(af, bfr[t], acc2[M][t], 0, 0, 0);
        }
    }

    #pragma unroll
    for (int M = 0; M < 2; ++M) {
        #pragma unroll
        for (int t = 0; t < 4; ++t) {
            int node = n0 + nloc[t];
            if (node < NN) {
                float4 v; v.x = acc2[M][t][0]; v.y = acc2[M][t][1]; v.z = acc2[M][t][2]; v.w = acc2[M][t][3];
                *(float4*)(out + (size_t)node * 128 + oc_q + M * 16) = v;
            }
        }
    }
}

extern "C" void kernel_launch(void* const* d_in, const int* in_sizes, int n_in,
                              void* d_out, int out_size, void* d_ws, size_t ws_size,
                              hipStream_t stream)
{
    const float* x   = (const float*)d_in[0];
    const float* pos = (const float*)d_in[1];
    const float* We1 = (const float*)d_in[2];
    const float* be1 = (const float*)d_in[3];
    const float* We2 = (const float*)d_in[4];
    const float* be2 = (const float*)d_in[5];
    const float* Wn1 = (const float*)d_in[6];
    const float* bn1 = (const float*)d_in[7];
    const float* Wn2 = (const float*)d_in[8];
    const float* bn2 = (const float*)d_in[9];
    const float* Wc  = (const float*)d_in[10];
    const float* bc  = (const float*)d_in[11];
    const int*   ei  = (const int*)d_in[12];
    float* out = (float*)d_out;

    char* p = (char*)d_ws;
    float* agg   = (float*)p;                  p += (size_t)NN * 128 * 4;   // 25.6 MB
    float* delta = (float*)p;                  p += (size_t)NN * 3 * 4;     // contiguous after agg
    int* cnt     = (int*)p;                    p += (size_t)NN * 4;         // contiguous after delta
    unsigned short* xbf = (unsigned short*)p;  p += (size_t)NN * 128 * 2;   // 12.8 MB
    unsigned short* wf1  = (unsigned short*)p; p += 65536;
    unsigned short* wf2  = (unsigned short*)p; p += 32768;
    unsigned short* wfn1 = (unsigned short*)p; p += 65536;
    unsigned short* wfn2 = (unsigned short*)p; p += 32768;
    int* off   = (int*)p;                      p += (size_t)(NN + 1) * 4 + 12;
    int* cur   = (int*)p;                      p += (size_t)NN * 4;
    int2* rc_slot = (int2*)p;

    // one memset covers agg + delta + cnt (contiguous)
    hipMemsetAsync(agg, 0, ((size_t)NN * 128 + (size_t)NN * 3 + NN) * 4, stream);

    prep_x_hist<<<3125, 256, 0, stream>>>(x, xbf, ei, cnt);
    prep_w<<<192, 64, 0, stream>>>(We1, We2, Wn1, Wn2, wf1, wf2, wfn1, wfn2);
    egnn_scan<<<1, 1024, 0, stream>>>(cnt, off, cur);
    egnn_scatter<<<NE / 256, 256, 0, stream>>>(ei, cur, rc_slot);
    egnn_edge_mfma<<<NE / 64, 256, 0, stream>>>(xbf, pos, wf1, wf2, We1, be1, be2,
                                                Wc, bc, rc_slot, agg, delta);
    egnn_node_mfma<<<(NN + 127) / 128, 512, 0, stream>>>(xbf, agg, delta, pos,
                                                         wfn1, wfn2, bn1, bn2, out);
}

// Round 8
// 458.303 us; speedup vs baseline: 1.3647x; 1.3647x over previous
//
#include <hip/hip_runtime.h>
#include <hip/hip_bf16.h>
#include <stdint.h>
#include <string.h>

#define NN 50000
#define NE 800000

typedef short bf8_t __attribute__((ext_vector_type(8)));
typedef float f32x4 __attribute__((ext_vector_type(4)));

// silu via native exp + v_rcp
__device__ __forceinline__ float silu_f(float v) {
    return v * __builtin_amdgcn_rcpf(1.0f + __expf(-v));
}

__device__ __forceinline__ unsigned int pack2bf(float a, float b) {
    __hip_bfloat162 h = __float22bfloat162_rn(make_float2(a, b));   // v_cvt_pk_bf16_f32
    unsigned int u; memcpy(&u, &h, 4);
    return u;
}

__device__ __forceinline__ float bf_lo(unsigned int u) { return __uint_as_float(u << 16); }
__device__ __forceinline__ float bf_hi(unsigned int u) { return __uint_as_float(u & 0xffff0000u); }

union U4B { uint4 u; bf8_t b; };
__device__ __forceinline__ bf8_t as_bf8(uint4 u) { U4B x; x.u = u; return x.b; }

__device__ __forceinline__ int kth_bit64(unsigned long long m, int k) {
    for (int i = 0; i < k; ++i) m &= m - 1;
    return __ffsll((long long)m) - 1;
}

// ---------------------------------------------------------------------------
// prep: x f32 -> bf16, fused with edge-row histogram
// ---------------------------------------------------------------------------
__global__ __launch_bounds__(256) void prep_x_hist(const float* __restrict__ x,
                                                   unsigned short* __restrict__ xbf,
                                                   const int* __restrict__ ei,
                                                   int* __restrict__ cnt) {
    size_t i = (size_t)blockIdx.x * 256 + threadIdx.x;
    const float4* s = (const float4*)(x + i * 8);
    float4 v0 = s[0], v1 = s[1];
    uint4 o;
    o.x = pack2bf(v0.x, v0.y); o.y = pack2bf(v0.z, v0.w);
    o.z = pack2bf(v1.x, v1.y); o.w = pack2bf(v1.z, v1.w);
    *(uint4*)(xbf + i * 8) = o;
    atomicAdd(&cnt[ei[i]], 1);
}

// ---------------------------------------------------------------------------
// prep: weight fragments in MFMA A-operand order (W^T), bf16.
// ---------------------------------------------------------------------------
__global__ __launch_bounds__(64) void prep_w(const float* __restrict__ We1,
                                             const float* __restrict__ We2,
                                             const float* __restrict__ Wn1,
                                             const float* __restrict__ Wn2,
                                             unsigned short* __restrict__ wf1,
                                             unsigned short* __restrict__ wf2,
                                             unsigned short* __restrict__ wfn1,
                                             unsigned short* __restrict__ wfn2) {
    int b = blockIdx.x, lane = threadIdx.x;
    int q = lane >> 4, c = lane & 15;
    const float* W; unsigned short* dst; int f;
    if (b < 64)       { W = We1; f = b;       dst = wf1  + (size_t)f * 512; }
    else if (b < 96)  { W = We2; f = b - 64;  dst = wf2  + (size_t)f * 512; }
    else if (b < 160) { W = Wn1; f = b - 96;  dst = wfn1 + (size_t)f * 512; }
    else              { W = Wn2; f = b - 160; dst = wfn2 + (size_t)f * 512; }
    int s = f >> 3, mf = f & 7;
    int k0 = s * 32 + q * 8, col = mf * 16 + c;
    float v[8];
    #pragma unroll
    for (int i = 0; i < 8; ++i) v[i] = W[(size_t)(k0 + i) * 128 + col];
    uint4 o;
    o.x = pack2bf(v[0], v[1]); o.y = pack2bf(v[2], v[3]);
    o.z = pack2bf(v[4], v[5]); o.w = pack2bf(v[6], v[7]);
    *(uint4*)(dst + lane * 8) = o;
}

// ---------------------------------------------------------------------------
// CSR build
// ---------------------------------------------------------------------------
__global__ __launch_bounds__(1024) void egnn_scan(const int* __restrict__ cnt,
                                                  int* __restrict__ off,
                                                  int* __restrict__ cur) {
    __shared__ int part[1024];
    const int t = threadIdx.x;
    const int CH = (NN + 1023) / 1024;
    int lo = t * CH, hi = lo + CH; if (hi > NN) hi = NN; if (lo > NN) lo = NN;
    int s = 0;
    for (int i = lo; i < hi; ++i) s += cnt[i];
    part[t] = s;
    __syncthreads();
    for (int d = 1; d < 1024; d <<= 1) {
        int v = (t >= d) ? part[t - d] : 0;
        __syncthreads();
        part[t] += v;
        __syncthreads();
    }
    int base = (t == 0) ? 0 : part[t - 1];
    for (int i = lo; i < hi; ++i) { off[i] = base; cur[i] = base; base += cnt[i]; }
    if (t == 1023) off[NN] = NE;
}

// scatter: materialize (row,col) pairs in CSR slot order as int2
__global__ __launch_bounds__(256) void egnn_scatter(const int* __restrict__ ei,
                                                    int* __restrict__ cur,
                                                    int2* __restrict__ rc_slot) {
    int e = blockIdx.x * 256 + threadIdx.x;
    if (e < NE) {
        int r = ei[e];
        int p = atomicAdd(&cur[r], 1);
        rc_slot[p] = make_int2(r, ei[NE + e]);
    }
}

// ---------------------------------------------------------------------------
// Edge MFMA kernel with fused segmented aggregation.
// Block = 64 CSR slots, 256 threads = 4 waves (P = col-quarter).
// __launch_bounds__(256,4): VGPR cap 128 -- (256,8) forced 32 VGPR and
// spilled ~1.5 GB to scratch (R7 post-mortem).
// ---------------------------------------------------------------------------
__global__ __launch_bounds__(256, 4) void egnn_edge_mfma(
    const unsigned short* __restrict__ xbf, const float* __restrict__ pos,
    const unsigned short* __restrict__ wf1, const unsigned short* __restrict__ wf2,
    const float* __restrict__ We1, const float* __restrict__ be1,
    const float* __restrict__ be2, const float* __restrict__ Wc,
    const float* __restrict__ bc,
    const int2* __restrict__ rc_slot,
    float* __restrict__ agg, float* __restrict__ delta)
{
    __shared__ __align__(16) char HsBuf[64 * 136 * 2];    // h1 tile, later m tile
    unsigned short* Hs = (unsigned short*)HsBuf;          // stride 136 (u16)
    unsigned int*  mls = (unsigned int*)HsBuf;            // stride 66  (u32)
    __shared__ int   rows_s[64], cols_s[64];
    __shared__ float rij_s[64][3];                        // becomes trans in place
    __shared__ float dij_s[64];
    __shared__ float wdot[64];
    __shared__ unsigned long long smask;
    __shared__ int firstPartial, lastPartial;

    const int tid = threadIdx.x;
    const int e0 = blockIdx.x * 64;

    if (tid < 64) {
        int2 rc = rc_slot[e0 + tid];
        rows_s[tid] = rc.x; cols_s[tid] = rc.y;
        float d = 0.f;
        #pragma unroll
        for (int k = 0; k < 3; ++k) {
            float rv = pos[rc.x * 3 + k] - pos[rc.y * 3 + k];
            rij_s[tid][k] = rv; d += rv * rv;
        }
        dij_s[tid] = d;
        wdot[tid] = 0.f;
    }
    __syncthreads();

    const int P = tid >> 6, lane = tid & 63;
    const int q = lane >> 4, e16 = lane & 15;
    const int oc_q = P * 32 + q * 4;

    int ridx[4], cidx[4], eloc[4];
    #pragma unroll
    for (int t = 0; t < 4; ++t) {
        int el = t * 16 + e16; eloc[t] = el;
        ridx[t] = rows_s[el]; cidx[t] = cols_s[el];
    }

    // ---- layer 1: K=256 MFMA; dij rank-1 + bias as f32 fixup ----
    f32x4 acc[2][4];
    #pragma unroll
    for (int M = 0; M < 2; ++M) {
        float4 bi = *(const float4*)(be1 + oc_q + M * 16);
        #pragma unroll
        for (int t = 0; t < 4; ++t) { acc[M][t][0] = bi.x; acc[M][t][1] = bi.y; acc[M][t][2] = bi.z; acc[M][t][3] = bi.w; }
    }

    #pragma unroll
    for (int s = 0; s < 8; ++s) {
        bf8_t bfr[4];
        #pragma unroll
        for (int t = 0; t < 4; ++t) {
            int node = (s < 4) ? ridx[t] : cidx[t];
            bfr[t] = as_bf8(*(const uint4*)(xbf + (size_t)node * 128 + (s & 3) * 32 + q * 8));
        }
        #pragma unroll
        for (int M = 0; M < 2; ++M) {
            bf8_t af = as_bf8(*(const uint4*)(wf1 + (size_t)(s * 8 + P * 2 + M) * 512 + lane * 8));
            #pragma unroll
            for (int t = 0; t < 4; ++t)
                acc[M][t] = __builtin_amdgcn_mfma_f32_16x16x32_bf16(af, bfr[t], acc[M][t], 0, 0, 0);
        }
    }

    #pragma unroll
    for (int M = 0; M < 2; ++M) {
        float4 w256 = *(const float4*)(We1 + (size_t)256 * 128 + oc_q + M * 16);
        #pragma unroll
        for (int t = 0; t < 4; ++t) {
            float d = dij_s[eloc[t]];
            float v0 = silu_f(acc[M][t][0] + d * w256.x);
            float v1 = silu_f(acc[M][t][1] + d * w256.y);
            float v2 = silu_f(acc[M][t][2] + d * w256.z);
            float v3 = silu_f(acc[M][t][3] + d * w256.w);
            uint2 pk; pk.x = pack2bf(v0, v1); pk.y = pack2bf(v2, v3);
            *(uint2*)(Hs + (size_t)eloc[t] * 136 + oc_q + M * 16) = pk;
        }
    }
    __syncthreads();

    // ---- layer 2: K=128 ----
    f32x4 acc2[2][4];
    #pragma unroll
    for (int M = 0; M < 2; ++M) {
        float4 bi = *(const float4*)(be2 + oc_q + M * 16);
        #pragma unroll
        for (int t = 0; t < 4; ++t) { acc2[M][t][0] = bi.x; acc2[M][t][1] = bi.y; acc2[M][t][2] = bi.z; acc2[M][t][3] = bi.w; }
    }

    #pragma unroll
    for (int s = 0; s < 4; ++s) {
        bf8_t bfr[4];
        #pragma unroll
        for (int t = 0; t < 4; ++t)
            bfr[t] = as_bf8(*(const uint4*)(Hs + (size_t)eloc[t] * 136 + s * 32 + q * 8));
        #pragma unroll
        for (int M = 0; M < 2; ++M) {
            bf8_t af = as_bf8(*(const uint4*)(wf2 + (size_t)(s * 8 + P * 2 + M) * 512 + lane * 8));
            #pragma unroll
            for (int t = 0; t < 4; ++t)
                acc2[M][t] = __builtin_amdgcn_mfma_f32_16x16x32_bf16(af, bfr[t], acc2[M][t], 0, 0, 0);
        }
    }
    __syncthreads();   // all Hs reads done before m overwrites the buffer

    // ---- epilogue: m = silu(.) -> LDS (mls); per-slot Wc dot partials ----
    float4 wcA = *(const float4*)(Wc + oc_q);
    float4 wcB = *(const float4*)(Wc + oc_q + 16);
    float part[4];
    #pragma unroll
    for (int t = 0; t < 4; ++t) part[t] = 0.f;

    #pragma unroll
    for (int M = 0; M < 2; ++M) {
        float4 wc = (M == 0) ? wcA : wcB;
        #pragma unroll
        for (int t = 0; t < 4; ++t) {
            float v0 = silu_f(acc2[M][t][0]);
            float v1 = silu_f(acc2[M][t][1]);
            float v2 = silu_f(acc2[M][t][2]);
            float v3 = silu_f(acc2[M][t][3]);
            part[t] += v0 * wc.x + v1 * wc.y + v2 * wc.z + v3 * wc.w;
            mls[(size_t)eloc[t] * 66 + P * 16 + M * 8 + q * 2]     = pack2bf(v0, v1);
            mls[(size_t)eloc[t] * 66 + P * 16 + M * 8 + q * 2 + 1] = pack2bf(v2, v3);
        }
    }
    #pragma unroll
    for (int t = 0; t < 4; ++t) {
        float p = part[t];
        p += __shfl_xor(p, 16);
        p += __shfl_xor(p, 32);
        if (q == 0) atomicAdd(&wdot[eloc[t]], p);
    }
    __syncthreads();   // mls + wdot complete

    // ---- per-slot trans (in place) + segment boundary detection ----
    if (tid < 64) {
        float wgt = silu_f(wdot[tid] + bc[0]);
        rij_s[tid][0] *= wgt; rij_s[tid][1] *= wgt; rij_s[tid][2] *= wgt;
        bool flag = (tid == 0) || (rows_s[tid] != rows_s[tid - 1]);
        unsigned long long b = __ballot(flag);
        if (lane == 0) {
            smask = b;
            firstPartial = (e0 > 0) && (rc_slot[e0 - 1].x == rows_s[0]);
            lastPartial  = (e0 + 64 < NE) && (rc_slot[e0 + 64].x == rows_s[63]);
        }
    }
    __syncthreads();

    // ---- segmented reduction: 4 groups x 64 col-pairs ----
    {
        const int c2 = tid & 63;          // u32 col pair -> cols 2c2, 2c2+1
        const int g  = tid >> 6;          // segment round-robin group
        unsigned long long m = smask;
        int nseg = __popcll(m);
        for (int k = g; k < nseg; k += 4) {
            int start = kth_bit64(m, k);
            int end   = (k + 1 < nseg) ? kth_bit64(m, k + 1) : 64;
            int node  = rows_s[start];
            float a0 = 0.f, a1 = 0.f;
            for (int s2 = start; s2 < end; ++s2) {
                unsigned int u = mls[(size_t)s2 * 66 + c2];
                a0 += bf_lo(u); a1 += bf_hi(u);
            }
            bool partial = (k == 0 && firstPartial) || (k == nseg - 1 && lastPartial);
            float* dst = agg + (size_t)node * 128 + c2 * 2;
            if (partial) { atomicAdd(dst, a0); atomicAdd(dst + 1, a1); }
            else         { *(float2*)dst = make_float2(a0, a1); }
            if (c2 == 0) {
                float d0 = 0.f, d1 = 0.f, d2 = 0.f;
                for (int s2 = start; s2 < end; ++s2) {
                    d0 += rij_s[s2][0]; d1 += rij_s[s2][1]; d2 += rij_s[s2][2];
                }
                float* dd = delta + (size_t)node * 3;
                if (partial) { atomicAdd(dd, d0); atomicAdd(dd + 1, d1); atomicAdd(dd + 2, d2); }
                else         { dd[0] = d0; dd[1] = d1; dd[2] = d2; }
            }
        }
    }
}

// ---------------------------------------------------------------------------
// Node MFMA kernel: x_new = silu([x|agg] @ Wn1 + bn1) @ Wn2 + bn2
// Reads agg f32 directly (in-register cvt); also writes pos_new.
// ---------------------------------------------------------------------------
__global__ __launch_bounds__(512, 4) void egnn_node_mfma(
    const unsigned short* __restrict__ xbf, const float* __restrict__ agg,
    const float* __restrict__ delta, const float* __restrict__ pos,
    const unsigned short* __restrict__ wfn1, const unsigned short* __restrict__ wfn2,
    const float* __restrict__ bn1, const float* __restrict__ bn2,
    float* __restrict__ out)
{
    __shared__ unsigned short Hs[128 * 136];

    const int tid = threadIdx.x;
    const int n0 = blockIdx.x * 128;

    // pos_new for this block's nodes (independent of the MLP)
    if (tid < 384) {
        int n = n0 + tid / 3, d = tid - 3 * (tid / 3);
        if (n < NN)
            out[(size_t)NN * 128 + (size_t)n * 3 + d] =
                pos[(size_t)n * 3 + d] + 0.01f * delta[(size_t)n * 3 + d];
    }

    const int w = tid >> 6, lane = tid & 63;
    const int P = w & 3, Q = w >> 2;
    const int q = lane >> 4, e16 = lane & 15;
    const int oc_q = P * 32 + q * 4;

    int nloc[4], nclamp[4];
    #pragma unroll
    for (int t = 0; t < 4; ++t) {
        int nl = Q * 64 + t * 16 + e16; nloc[t] = nl;
        int node = n0 + nl; nclamp[t] = (node >= NN) ? NN - 1 : node;
    }

    f32x4 acc[2][4];
    #pragma unroll
    for (int M = 0; M < 2; ++M) {
        float4 bi = *(const float4*)(bn1 + oc_q + M * 16);
        #pragma unroll
        for (int t = 0; t < 4; ++t) { acc[M][t][0] = bi.x; acc[M][t][1] = bi.y; acc[M][t][2] = bi.z; acc[M][t][3] = bi.w; }
    }

    #pragma unroll
    for (int s = 0; s < 8; ++s) {
        bf8_t bfr[4];
        #pragma unroll
        for (int t = 0; t < 4; ++t) {
            if (s < 4) {
                bfr[t] = as_bf8(*(const uint4*)(xbf + (size_t)nclamp[t] * 128 + (s & 3) * 32 + q * 8));
            } else {
                const float* base = agg + (size_t)nclamp[t] * 128 + (s & 3) * 32 + q * 8;
                float4 a0 = *(const float4*)base;
                float4 a1 = *(const float4*)(base + 4);
                uint4 o;
                o.x = pack2bf(a0.x, a0.y); o.y = pack2bf(a0.z, a0.w);
                o.z = pack2bf(a1.x, a1.y); o.w = pack2bf(a1.z, a1.w);
                bfr[t] = as_bf8(o);
            }
        }
        #pragma unroll
        for (int M = 0; M < 2; ++M) {
            bf8_t af = as_bf8(*(const uint4*)(wfn1 + (size_t)(s * 8 + P * 2 + M) * 512 + lane * 8));
            #pragma unroll
            for (int t = 0; t < 4; ++t)
                acc[M][t] = __builtin_amdgcn_mfma_f32_16x16x32_bf16(af, bfr[t], acc[M][t], 0, 0, 0);
        }
    }

    #pragma unroll
    for (int M = 0; M < 2; ++M) {
        #pragma unroll
        for (int t = 0; t < 4; ++t) {
            float v0 = silu_f(acc[M][t][0]);
            float v1 = silu_f(acc[M][t][1]);
            float v2 = silu_f(acc[M][t][2]);
            float v3 = silu_f(acc[M][t][3]);
            uint2 pk; pk.x = pack2bf(v0, v1); pk.y = pack2bf(v2, v3);
            *(uint2*)(Hs + (size_t)nloc[t] * 136 + oc_q + M * 16) = pk;
        }
    }
    __syncthreads();

    f32x4 acc2[2][4];
    #pragma unroll
    for (int M = 0; M < 2; ++M) {
        float4 bi = *(const float4*)(bn2 + oc_q + M * 16);
        #pragma unroll
        for (int t = 0; t < 4; ++t) { acc2[M][t][0] = bi.x; acc2[M][t][1] = bi.y; acc2[M][t][2] = bi.z; acc2[M][t][3] = bi.w; }
    }

    #pragma unroll
    for (int s = 0; s < 4; ++s) {
        bf8_t bfr[4];
        #pragma unroll
        for (int t = 0; t < 4; ++t)
            bfr[t] = as_bf8(*(const uint4*)(Hs + (size_t)nloc[t] * 136 + s * 32 + q * 8));
        #pragma unroll
        for (int M = 0; M < 2; ++M) {
            bf8_t af = as_bf8(*(const uint4*)(wfn2 + (size_t)(s * 8 + P * 2 + M) * 512 + lane * 8));
            #pragma unroll
            for (int t = 0; t < 4; ++t)
                acc2[M][t] = __builtin_amdgcn_mfma_f32_16x16x32_bf16(af, bfr[t], acc2[M][t], 0, 0, 0);
        }
    }

    #pragma unroll
    for (int M = 0; M < 2; ++M) {
        #pragma unroll
        for (int t = 0; t < 4; ++t) {
            int node = n0 + nloc[t];
            if (node < NN) {
                float4 v; v.x = acc2[M][t][0]; v.y = acc2[M][t][1]; v.z = acc2[M][t][2]; v.w = acc2[M][t][3];
                *(float4*)(out + (size_t)node * 128 + oc_q + M * 16) = v;
            }
        }
    }
}

extern "C" void kernel_launch(void* const* d_in, const int* in_sizes, int n_in,
                              void* d_out, int out_size, void* d_ws, size_t ws_size,
                              hipStream_t stream)
{
    const float* x   = (const float*)d_in[0];
    const float* pos = (const float*)d_in[1];
    const float* We1 = (const float*)d_in[2];
    const float* be1 = (const float*)d_in[3];
    const float* We2 = (const float*)d_in[4];
    const float* be2 = (const float*)d_in[5];
    const float* Wn1 = (const float*)d_in[6];
    const float* bn1 = (const float*)d_in[7];
    const float* Wn2 = (const float*)d_in[8];
    const float* bn2 = (const float*)d_in[9];
    const float* Wc  = (const float*)d_in[10];
    const float* bc  = (const float*)d_in[11];
    const int*   ei  = (const int*)d_in[12];
    float* out = (float*)d_out;

    char* p = (char*)d_ws;
    float* agg   = (float*)p;                  p += (size_t)NN * 128 * 4;   // 25.6 MB
    float* delta = (float*)p;                  p += (size_t)NN * 3 * 4;     // contiguous after agg
    int* cnt     = (int*)p;                    p += (size_t)NN * 4;         // contiguous after delta
    unsigned short* xbf = (unsigned short*)p;  p += (size_t)NN * 128 * 2;   // 12.8 MB
    unsigned short* wf1  = (unsigned short*)p; p += 65536;
    unsigned short* wf2  = (unsigned short*)p; p += 32768;
    unsigned short* wfn1 = (unsigned short*)p; p += 65536;
    unsigned short* wfn2 = (unsigned short*)p; p += 32768;
    int* off   = (int*)p;                      p += (size_t)(NN + 1) * 4 + 12;
    int* cur   = (int*)p;                      p += (size_t)NN * 4;
    int2* rc_slot = (int2*)p;

    // one memset covers agg + delta + cnt (contiguous)
    hipMemsetAsync(agg, 0, ((size_t)NN * 128 + (size_t)NN * 3 + NN) * 4, stream);

    prep_x_hist<<<3125, 256, 0, stream>>>(x, xbf, ei, cnt);
    prep_w<<<192, 64, 0, stream>>>(We1, We2, Wn1, Wn2, wf1, wf2, wfn1, wfn2);
    egnn_scan<<<1, 1024, 0, stream>>>(cnt, off, cur);
    egnn_scatter<<<NE / 256, 256, 0, stream>>>(ei, cur, rc_slot);
    egnn_edge_mfma<<<NE / 64, 256, 0, stream>>>(xbf, pos, wf1, wf2, We1, be1, be2,
                                                Wc, bc, rc_slot, agg, delta);
    egnn_node_mfma<<<(NN + 127) / 128, 512, 0, stream>>>(xbf, agg, delta, pos,
                                                         wfn1, wfn2, bn1, bn2, out);
}

// Round 9
// 356.869 us; speedup vs baseline: 1.7526x; 1.2842x over previous
//
#include <hip/hip_runtime.h>
#include <hip/hip_bf16.h>
#include <stdint.h>
#include <string.h>

#define NN 50000
#define NE 800000
#define SCAN_B 200
#define SCAN_CH 250

typedef short bf8_t __attribute__((ext_vector_type(8)));
typedef float f32x4 __attribute__((ext_vector_type(4)));

// silu via native exp + v_rcp
__device__ __forceinline__ float silu_f(float v) {
    return v * __builtin_amdgcn_rcpf(1.0f + __expf(-v));
}

__device__ __forceinline__ unsigned int pack2bf(float a, float b) {
    __hip_bfloat162 h = __float22bfloat162_rn(make_float2(a, b));   // v_cvt_pk_bf16_f32
    unsigned int u; memcpy(&u, &h, 4);
    return u;
}

__device__ __forceinline__ float bf_lo(unsigned int u) { return __uint_as_float(u << 16); }
__device__ __forceinline__ float bf_hi(unsigned int u) { return __uint_as_float(u & 0xffff0000u); }

union U4B { uint4 u; bf8_t b; };
__device__ __forceinline__ bf8_t as_bf8(uint4 u) { U4B x; x.u = u; return x.b; }

__device__ __forceinline__ int kth_bit64(unsigned long long m, int k) {
    for (int i = 0; i < k; ++i) m &= m - 1;
    return __ffsll((long long)m) - 1;
}

// ---------------------------------------------------------------------------
// prep: x f32 -> bf16, fused with edge-row histogram
// ---------------------------------------------------------------------------
__global__ __launch_bounds__(256) void prep_x_hist(const float* __restrict__ x,
                                                   unsigned short* __restrict__ xbf,
                                                   const int* __restrict__ ei,
                                                   int* __restrict__ cnt) {
    size_t i = (size_t)blockIdx.x * 256 + threadIdx.x;
    const float4* s = (const float4*)(x + i * 8);
    float4 v0 = s[0], v1 = s[1];
    uint4 o;
    o.x = pack2bf(v0.x, v0.y); o.y = pack2bf(v0.z, v0.w);
    o.z = pack2bf(v1.x, v1.y); o.w = pack2bf(v1.z, v1.w);
    *(uint4*)(xbf + i * 8) = o;
    atomicAdd(&cnt[ei[i]], 1);
}

// ---------------------------------------------------------------------------
// prep: weight fragments in MFMA A-operand order (W^T), bf16.
// ---------------------------------------------------------------------------
__global__ __launch_bounds__(64) void prep_w(const float* __restrict__ We1,
                                             const float* __restrict__ We2,
                                             const float* __restrict__ Wn1,
                                             const float* __restrict__ Wn2,
                                             unsigned short* __restrict__ wf1,
                                             unsigned short* __restrict__ wf2,
                                             unsigned short* __restrict__ wfn1,
                                             unsigned short* __restrict__ wfn2) {
    int b = blockIdx.x, lane = threadIdx.x;
    int q = lane >> 4, c = lane & 15;
    const float* W; unsigned short* dst; int f;
    if (b < 64)       { W = We1; f = b;       dst = wf1  + (size_t)f * 512; }
    else if (b < 96)  { W = We2; f = b - 64;  dst = wf2  + (size_t)f * 512; }
    else if (b < 160) { W = Wn1; f = b - 96;  dst = wfn1 + (size_t)f * 512; }
    else              { W = Wn2; f = b - 160; dst = wfn2 + (size_t)f * 512; }
    int s = f >> 3, mf = f & 7;
    int k0 = s * 32 + q * 8, col = mf * 16 + c;
    float v[8];
    #pragma unroll
    for (int i = 0; i < 8; ++i) v[i] = W[(size_t)(k0 + i) * 128 + col];
    uint4 o;
    o.x = pack2bf(v[0], v[1]); o.y = pack2bf(v[2], v[3]);
    o.z = pack2bf(v[4], v[5]); o.w = pack2bf(v[6], v[7]);
    *(uint4*)(dst + lane * 8) = o;
}

// ---------------------------------------------------------------------------
// Parallel CSR scan: (1) per-chunk sums, (2) per-chunk block-scan + write
// ---------------------------------------------------------------------------
__global__ __launch_bounds__(256) void scan_bsum(const int* __restrict__ cnt,
                                                 int* __restrict__ bsum) {
    __shared__ int red[4];
    int b = blockIdx.x, tid = threadIdx.x;
    int n = b * SCAN_CH + tid;
    int v = (tid < SCAN_CH) ? cnt[n] : 0;
    #pragma unroll
    for (int o = 32; o; o >>= 1) v += __shfl_down(v, o);
    if ((tid & 63) == 0) red[tid >> 6] = v;
    __syncthreads();
    if (tid == 0) bsum[b] = red[0] + red[1] + red[2] + red[3];
}

__global__ __launch_bounds__(256) void scan_write(const int* __restrict__ cnt,
                                                  const int* __restrict__ bsum,
                                                  int* __restrict__ off,
                                                  int* __restrict__ cur) {
    __shared__ int part[256];
    __shared__ int basered[4];
    int b = blockIdx.x, tid = threadIdx.x;
    // base = sum of bsum[0..b-1]
    int bv = (tid < b) ? bsum[tid] : 0;
    #pragma unroll
    for (int o = 32; o; o >>= 1) bv += __shfl_down(bv, o);
    if ((tid & 63) == 0) basered[tid >> 6] = bv;
    __syncthreads();
    int base = basered[0] + basered[1] + basered[2] + basered[3];
    // block inclusive scan over this chunk's counts
    int n = b * SCAN_CH + tid;
    int c = (tid < SCAN_CH) ? cnt[n] : 0;
    part[tid] = c;
    __syncthreads();
    #pragma unroll
    for (int d = 1; d < 256; d <<= 1) {
        int v = (tid >= d) ? part[tid - d] : 0;
        __syncthreads();
        part[tid] += v;
        __syncthreads();
    }
    if (tid < SCAN_CH) {
        int excl = base + part[tid] - c;
        off[n] = excl; cur[n] = excl;
    }
    if (b == SCAN_B - 1 && tid == SCAN_CH) off[NN] = NE;
}

// scatter: materialize (row,col) pairs in CSR slot order as int2
__global__ __launch_bounds__(256) void egnn_scatter(const int* __restrict__ ei,
                                                    int* __restrict__ cur,
                                                    int2* __restrict__ rc_slot) {
    int e = blockIdx.x * 256 + threadIdx.x;
    if (e < NE) {
        int r = ei[e];
        int p = atomicAdd(&cur[r], 1);
        rc_slot[p] = make_int2(r, ei[NE + e]);
    }
}

// ---------------------------------------------------------------------------
// Edge MFMA kernel with fused segmented aggregation.
// Block = 64 CSR slots, 256 threads = 4 waves (P = col-quarter).
// 32-bit byte offsets for all gathers (buffers << 4GB) -> saddr-form loads.
// ---------------------------------------------------------------------------
__global__ __launch_bounds__(256, 4) void egnn_edge_mfma(
    const unsigned short* __restrict__ xbf, const float* __restrict__ pos,
    const unsigned short* __restrict__ wf1, const unsigned short* __restrict__ wf2,
    const float* __restrict__ We1, const float* __restrict__ be1,
    const float* __restrict__ be2, const float* __restrict__ Wc,
    const float* __restrict__ bc,
    const int2* __restrict__ rc_slot,
    float* __restrict__ agg, float* __restrict__ delta)
{
    __shared__ __align__(16) char HsBuf[64 * 136 * 2];    // h1 tile, later m tile
    unsigned short* Hs = (unsigned short*)HsBuf;          // stride 136 (u16)
    unsigned int*  mls = (unsigned int*)HsBuf;            // stride 66  (u32)
    __shared__ int   rows_s[64], cols_s[64];
    __shared__ float rij_s[64][3];                        // becomes trans in place
    __shared__ float dij_s[64];
    __shared__ float wdot[64];
    __shared__ unsigned long long smask;
    __shared__ int firstPartial, lastPartial;

    const int tid = threadIdx.x;
    const int e0 = blockIdx.x * 64;
    const char* xb = (const char*)xbf;
    const char* w1 = (const char*)wf1;
    const char* w2 = (const char*)wf2;

    if (tid < 64) {
        int2 rc = rc_slot[e0 + tid];
        rows_s[tid] = rc.x; cols_s[tid] = rc.y;
        float d = 0.f;
        #pragma unroll
        for (int k = 0; k < 3; ++k) {
            float rv = pos[rc.x * 3 + k] - pos[rc.y * 3 + k];
            rij_s[tid][k] = rv; d += rv * rv;
        }
        dij_s[tid] = d;
        wdot[tid] = 0.f;
    }
    __syncthreads();

    const int P = tid >> 6, lane = tid & 63;
    const int q = lane >> 4, e16 = lane & 15;
    const int oc_q = P * 32 + q * 4;
    const unsigned qb = (unsigned)(q * 16);               // q*8 elems * 2B

    unsigned roff[4], coff[4]; int eloc[4];
    #pragma unroll
    for (int t = 0; t < 4; ++t) {
        int el = t * 16 + e16; eloc[t] = el;
        roff[t] = ((unsigned)rows_s[el] << 8) + qb;
        coff[t] = ((unsigned)cols_s[el] << 8) + qb;
    }

    // ---- layer 1: K=256 MFMA; dij rank-1 + bias as f32 fixup ----
    f32x4 acc[2][4];
    #pragma unroll
    for (int M = 0; M < 2; ++M) {
        float4 bi = *(const float4*)(be1 + oc_q + M * 16);
        #pragma unroll
        for (int t = 0; t < 4; ++t) { acc[M][t][0] = bi.x; acc[M][t][1] = bi.y; acc[M][t][2] = bi.z; acc[M][t][3] = bi.w; }
    }

    #pragma unroll
    for (int s = 0; s < 8; ++s) {
        bf8_t bfr[4];
        #pragma unroll
        for (int t = 0; t < 4; ++t) {
            unsigned noff = ((s < 4) ? roff[t] : coff[t]) + (unsigned)((s & 3) * 64);
            bfr[t] = as_bf8(*(const uint4*)(xb + noff));
        }
        #pragma unroll
        for (int M = 0; M < 2; ++M) {
            unsigned woff = ((unsigned)(s * 8 + P * 2 + M) << 10) + ((unsigned)lane << 4);
            bf8_t af = as_bf8(*(const uint4*)(w1 + woff));
            #pragma unroll
            for (int t = 0; t < 4; ++t)
                acc[M][t] = __builtin_amdgcn_mfma_f32_16x16x32_bf16(af, bfr[t], acc[M][t], 0, 0, 0);
        }
    }

    #pragma unroll
    for (int M = 0; M < 2; ++M) {
        float4 w256 = *(const float4*)(We1 + (size_t)256 * 128 + oc_q + M * 16);
        #pragma unroll
        for (int t = 0; t < 4; ++t) {
            float d = dij_s[eloc[t]];
            float v0 = silu_f(acc[M][t][0] + d * w256.x);
            float v1 = silu_f(acc[M][t][1] + d * w256.y);
            float v2 = silu_f(acc[M][t][2] + d * w256.z);
            float v3 = silu_f(acc[M][t][3] + d * w256.w);
            uint2 pk; pk.x = pack2bf(v0, v1); pk.y = pack2bf(v2, v3);
            *(uint2*)(Hs + eloc[t] * 136 + oc_q + M * 16) = pk;
        }
    }
    __syncthreads();

    // ---- layer 2: K=128 ----
    f32x4 acc2[2][4];
    #pragma unroll
    for (int M = 0; M < 2; ++M) {
        float4 bi = *(const float4*)(be2 + oc_q + M * 16);
        #pragma unroll
        for (int t = 0; t < 4; ++t) { acc2[M][t][0] = bi.x; acc2[M][t][1] = bi.y; acc2[M][t][2] = bi.z; acc2[M][t][3] = bi.w; }
    }

    #pragma unroll
    for (int s = 0; s < 4; ++s) {
        bf8_t bfr[4];
        #pragma unroll
        for (int t = 0; t < 4; ++t)
            bfr[t] = as_bf8(*(const uint4*)(Hs + eloc[t] * 136 + s * 32 + q * 8));
        #pragma unroll
        for (int M = 0; M < 2; ++M) {
            unsigned woff = ((unsigned)(s * 8 + P * 2 + M) << 10) + ((unsigned)lane << 4);
            bf8_t af = as_bf8(*(const uint4*)(w2 + woff));
            #pragma unroll
            for (int t = 0; t < 4; ++t)
                acc2[M][t] = __builtin_amdgcn_mfma_f32_16x16x32_bf16(af, bfr[t], acc2[M][t], 0, 0, 0);
        }
    }
    __syncthreads();   // all Hs reads done before m overwrites the buffer

    // ---- epilogue: m = silu(.) -> LDS (mls); per-slot Wc dot partials ----
    float4 wcA = *(const float4*)(Wc + oc_q);
    float4 wcB = *(const float4*)(Wc + oc_q + 16);
    float part[4];
    #pragma unroll
    for (int t = 0; t < 4; ++t) part[t] = 0.f;

    #pragma unroll
    for (int M = 0; M < 2; ++M) {
        float4 wc = (M == 0) ? wcA : wcB;
        #pragma unroll
        for (int t = 0; t < 4; ++t) {
            float v0 = silu_f(acc2[M][t][0]);
            float v1 = silu_f(acc2[M][t][1]);
            float v2 = silu_f(acc2[M][t][2]);
            float v3 = silu_f(acc2[M][t][3]);
            part[t] += v0 * wc.x + v1 * wc.y + v2 * wc.z + v3 * wc.w;
            mls[eloc[t] * 66 + P * 16 + M * 8 + q * 2]     = pack2bf(v0, v1);
            mls[eloc[t] * 66 + P * 16 + M * 8 + q * 2 + 1] = pack2bf(v2, v3);
        }
    }
    #pragma unroll
    for (int t = 0; t < 4; ++t) {
        float p = part[t];
        p += __shfl_xor(p, 16);
        p += __shfl_xor(p, 32);
        if (q == 0) atomicAdd(&wdot[eloc[t]], p);
    }
    __syncthreads();   // mls + wdot complete

    // ---- per-slot trans (in place) + segment boundary detection ----
    if (tid < 64) {
        float wgt = silu_f(wdot[tid] + bc[0]);
        rij_s[tid][0] *= wgt; rij_s[tid][1] *= wgt; rij_s[tid][2] *= wgt;
        bool flag = (tid == 0) || (rows_s[tid] != rows_s[tid - 1]);
        unsigned long long b = __ballot(flag);
        if (lane == 0) {
            smask = b;
            firstPartial = (e0 > 0) && (rc_slot[e0 - 1].x == rows_s[0]);
            lastPartial  = (e0 + 64 < NE) && (rc_slot[e0 + 64].x == rows_s[63]);
        }
    }
    __syncthreads();

    // ---- segmented reduction: 4 groups x 64 col-pairs ----
    {
        const int c2 = tid & 63;          // u32 col pair -> cols 2c2, 2c2+1
        const int g  = tid >> 6;          // segment round-robin group
        unsigned long long m = smask;
        int nseg = __popcll(m);
        for (int k = g; k < nseg; k += 4) {
            int start = kth_bit64(m, k);
            int end   = (k + 1 < nseg) ? kth_bit64(m, k + 1) : 64;
            int node  = rows_s[start];
            float a0 = 0.f, a1 = 0.f;
            for (int s2 = start; s2 < end; ++s2) {
                unsigned int u = mls[s2 * 66 + c2];
                a0 += bf_lo(u); a1 += bf_hi(u);
            }
            bool partial = (k == 0 && firstPartial) || (k == nseg - 1 && lastPartial);
            float* dst = agg + (size_t)node * 128 + c2 * 2;
            if (partial) { atomicAdd(dst, a0); atomicAdd(dst + 1, a1); }
            else         { *(float2*)dst = make_float2(a0, a1); }
            if (c2 == 0) {
                float d0 = 0.f, d1 = 0.f, d2 = 0.f;
                for (int s2 = start; s2 < end; ++s2) {
                    d0 += rij_s[s2][0]; d1 += rij_s[s2][1]; d2 += rij_s[s2][2];
                }
                float* dd = delta + (size_t)node * 3;
                if (partial) { atomicAdd(dd, d0); atomicAdd(dd + 1, d1); atomicAdd(dd + 2, d2); }
                else         { dd[0] = d0; dd[1] = d1; dd[2] = d2; }
            }
        }
    }
}

// ---------------------------------------------------------------------------
// Node MFMA kernel: 64-node blocks, 256 threads (P = col-quarter).
// Reads agg f32 directly (in-register cvt); also writes pos_new.
// ---------------------------------------------------------------------------
__global__ __launch_bounds__(256, 4) void egnn_node_mfma(
    const unsigned short* __restrict__ xbf, const float* __restrict__ agg,
    const float* __restrict__ delta, const float* __restrict__ pos,
    const unsigned short* __restrict__ wfn1, const unsigned short* __restrict__ wfn2,
    const float* __restrict__ bn1, const float* __restrict__ bn2,
    float* __restrict__ out)
{
    __shared__ unsigned short Hs[64 * 136];

    const int tid = threadIdx.x;
    const int n0 = blockIdx.x * 64;
    const char* xb = (const char*)xbf;
    const char* ab = (const char*)agg;
    const char* w1 = (const char*)wfn1;
    const char* w2 = (const char*)wfn2;

    // pos_new for this block's nodes (independent of the MLP)
    if (tid < 192) {
        int n = n0 + tid / 3, d = tid - 3 * (tid / 3);
        if (n < NN)
            out[(size_t)NN * 128 + (size_t)n * 3 + d] =
                pos[(size_t)n * 3 + d] + 0.01f * delta[(size_t)n * 3 + d];
    }

    const int P = tid >> 6, lane = tid & 63;
    const int q = lane >> 4, e16 = lane & 15;
    const int oc_q = P * 32 + q * 4;

    int nloc[4]; unsigned nb[4];
    #pragma unroll
    for (int t = 0; t < 4; ++t) {
        int nl = t * 16 + e16; nloc[t] = nl;
        int node = n0 + nl; if (node >= NN) node = NN - 1;
        nb[t] = (unsigned)node;
    }

    f32x4 acc[2][4];
    #pragma unroll
    for (int M = 0; M < 2; ++M) {
        float4 bi = *(const float4*)(bn1 + oc_q + M * 16);
        #pragma unroll
        for (int t = 0; t < 4; ++t) { acc[M][t][0] = bi.x; acc[M][t][1] = bi.y; acc[M][t][2] = bi.z; acc[M][t][3] = bi.w; }
    }

    #pragma unroll
    for (int s = 0; s < 8; ++s) {
        bf8_t bfr[4];
        #pragma unroll
        for (int t = 0; t < 4; ++t) {
            if (s < 4) {
                unsigned noff = (nb[t] << 8) + (unsigned)((s & 3) * 64 + q * 16);
                bfr[t] = as_bf8(*(const uint4*)(xb + noff));
            } else {
                unsigned aoff = (nb[t] << 9) + (unsigned)(((s & 3) * 32 + q * 8) * 4);
                float4 a0 = *(const float4*)(ab + aoff);
                float4 a1 = *(const float4*)(ab + aoff + 16);
                uint4 o;
                o.x = pack2bf(a0.x, a0.y); o.y = pack2bf(a0.z, a0.w);
                o.z = pack2bf(a1.x, a1.y); o.w = pack2bf(a1.z, a1.w);
                bfr[t] = as_bf8(o);
            }
        }
        #pragma unroll
        for (int M = 0; M < 2; ++M) {
            unsigned woff = ((unsigned)(s * 8 + P * 2 + M) << 10) + ((unsigned)lane << 4);
            bf8_t af = as_bf8(*(const uint4*)(w1 + woff));
            #pragma unroll
            for (int t = 0; t < 4; ++t)
                acc[M][t] = __builtin_amdgcn_mfma_f32_16x16x32_bf16(af, bfr[t], acc[M][t], 0, 0, 0);
        }
    }

    #pragma unroll
    for (int M = 0; M < 2; ++M) {
        #pragma unroll
        for (int t = 0; t < 4; ++t) {
            float v0 = silu_f(acc[M][t][0]);
            float v1 = silu_f(acc[M][t][1]);
            float v2 = silu_f(acc[M][t][2]);
            float v3 = silu_f(acc[M][t][3]);
            uint2 pk; pk.x = pack2bf(v0, v1); pk.y = pack2bf(v2, v3);
            *(uint2*)(Hs + nloc[t] * 136 + oc_q + M * 16) = pk;
        }
    }
    __syncthreads();

    f32x4 acc2[2][4];
    #pragma unroll
    for (int M = 0; M < 2; ++M) {
        float4 bi = *(const float4*)(bn2 + oc_q + M * 16);
        #pragma unroll
        for (int t = 0; t < 4; ++t) { acc2[M][t][0] = bi.x; acc2[M][t][1] = bi.y; acc2[M][t][2] = bi.z; acc2[M][t][3] = bi.w; }
    }

    #pragma unroll
    for (int s = 0; s < 4; ++s) {
        bf8_t bfr[4];
        #pragma unroll
        for (int t = 0; t < 4; ++t)
            bfr[t] = as_bf8(*(const uint4*)(Hs + nloc[t] * 136 + s * 32 + q * 8));
        #pragma unroll
        for (int M = 0; M < 2; ++M) {
            unsigned woff = ((unsigned)(s * 8 + P * 2 + M) << 10) + ((unsigned)lane << 4);
            bf8_t af = as_bf8(*(const uint4*)(w2 + woff));
            #pragma unroll
            for (int t = 0; t < 4; ++t)
                acc2[M][t] = __builtin_amdgcn_mfma_f32_16x16x32_bf16(af, bfr[t], acc2[M][t], 0, 0, 0);
        }
    }

    #pragma unroll
    for (int M = 0; M < 2; ++M) {
        #pragma unroll
        for (int t = 0; t < 4; ++t) {
            int node = n0 + nloc[t];
            if (node < NN) {
                float4 v; v.x = acc2[M][t][0]; v.y = acc2[M][t][1]; v.z = acc2[M][t][2]; v.w = acc2[M][t][3];
                *(float4*)(out + (size_t)node * 128 + oc_q + M * 16) = v;
            }
        }
    }
}

extern "C" void kernel_launch(void* const* d_in, const int* in_sizes, int n_in,
                              void* d_out, int out_size, void* d_ws, size_t ws_size,
                              hipStream_t stream)
{
    const float* x   = (const float*)d_in[0];
    const float* pos = (const float*)d_in[1];
    const float* We1 = (const float*)d_in[2];
    const float* be1 = (const float*)d_in[3];
    const float* We2 = (const float*)d_in[4];
    const float* be2 = (const float*)d_in[5];
    const float* Wn1 = (const float*)d_in[6];
    const float* bn1 = (const float*)d_in[7];
    const float* Wn2 = (const float*)d_in[8];
    const float* bn2 = (const float*)d_in[9];
    const float* Wc  = (const float*)d_in[10];
    const float* bc  = (const float*)d_in[11];
    const int*   ei  = (const int*)d_in[12];
    float* out = (float*)d_out;

    char* p = (char*)d_ws;
    float* agg   = (float*)p;                  p += (size_t)NN * 128 * 4;   // 25.6 MB
    float* delta = (float*)p;                  p += (size_t)NN * 3 * 4;     // contiguous after agg
    int* cnt     = (int*)p;                    p += (size_t)NN * 4;         // contiguous after delta
    unsigned short* xbf = (unsigned short*)p;  p += (size_t)NN * 128 * 2;   // 12.8 MB
    unsigned short* wf1  = (unsigned short*)p; p += 65536;
    unsigned short* wf2  = (unsigned short*)p; p += 32768;
    unsigned short* wfn1 = (unsigned short*)p; p += 65536;
    unsigned short* wfn2 = (unsigned short*)p; p += 32768;
    int* off   = (int*)p;                      p += (size_t)(NN + 1) * 4 + 12;
    int* cur   = (int*)p;                      p += (size_t)NN * 4;
    int* bsum  = (int*)p;                      p += (size_t)SCAN_B * 4;
    int2* rc_slot = (int2*)p;

    // one memset covers agg + delta + cnt (contiguous)
    hipMemsetAsync(agg, 0, ((size_t)NN * 128 + (size_t)NN * 3 + NN) * 4, stream);

    prep_x_hist<<<3125, 256, 0, stream>>>(x, xbf, ei, cnt);
    prep_w<<<192, 64, 0, stream>>>(We1, We2, Wn1, Wn2, wf1, wf2, wfn1, wfn2);
    scan_bsum<<<SCAN_B, 256, 0, stream>>>(cnt, bsum);
    scan_write<<<SCAN_B, 256, 0, stream>>>(cnt, bsum, off, cur);
    egnn_scatter<<<NE / 256, 256, 0, stream>>>(ei, cur, rc_slot);
    egnn_edge_mfma<<<NE / 64, 256, 0, stream>>>(xbf, pos, wf1, wf2, We1, be1, be2,
                                                Wc, bc, rc_slot, agg, delta);
    egnn_node_mfma<<<(NN + 63) / 64, 256, 0, stream>>>(xbf, agg, delta, pos,
                                                       wfn1, wfn2, bn1, bn2, out);
}